// Round 1
// baseline (505.337 us; speedup 1.0000x reference)
//
#include <hip/hip_runtime.h>

#define N_NODES 100000
#define N_EDGES 800000
#define F 128
#define NB 16   // nodes per block in main kernel; 100000 % 16 == 0

// ---------------- CSR build ----------------

__global__ void hist_kernel(const int* __restrict__ dst, int* __restrict__ count, int E) {
    int e = blockIdx.x * 256 + threadIdx.x;
    if (e < E) atomicAdd(&count[dst[e]], 1);
}

// Per-block exclusive scan of 1024 elements (256 thr x 4), block totals to bsums.
__global__ void scan1_kernel(const int* __restrict__ count, int* __restrict__ rowptr,
                             int* __restrict__ bsums, int N) {
    __shared__ int s[256];
    int tid = threadIdx.x;
    int base = blockIdx.x * 1024 + tid * 4;
    int c[4];
    int tsum = 0;
#pragma unroll
    for (int j = 0; j < 4; ++j) {
        int idx = base + j;
        c[j] = (idx < N) ? count[idx] : 0;
        tsum += c[j];
    }
    s[tid] = tsum;
    __syncthreads();
    for (int off = 1; off < 256; off <<= 1) {
        int u = (tid >= off) ? s[tid - off] : 0;
        __syncthreads();
        s[tid] += u;
        __syncthreads();
    }
    int incl = s[tid];
    int run = incl - tsum;  // exclusive offset of this thread within block
#pragma unroll
    for (int j = 0; j < 4; ++j) {
        int idx = base + j;
        if (idx < N) rowptr[idx] = run;
        run += c[j];
    }
    if (tid == 255) bsums[blockIdx.x] = incl;  // block total
}

// Exclusive scan of block sums (nb <= 256), in place.
__global__ void scan2_kernel(int* __restrict__ bsums, int nb) {
    __shared__ int s[256];
    int tid = threadIdx.x;
    int v = (tid < nb) ? bsums[tid] : 0;
    s[tid] = v;
    __syncthreads();
    for (int off = 1; off < 256; off <<= 1) {
        int u = (tid >= off) ? s[tid - off] : 0;
        __syncthreads();
        s[tid] += u;
        __syncthreads();
    }
    int excl = s[tid] - v;
    if (tid < nb) bsums[tid] = excl;
}

__global__ void scan3_kernel(int* __restrict__ rowptr, const int* __restrict__ bsums,
                             int* __restrict__ cursor, int N) {
    int i = blockIdx.x * 256 + threadIdx.x;
    if (i < N) {
        int r = rowptr[i] + bsums[i >> 10];
        rowptr[i] = r;
        cursor[i] = r;
    }
}

__global__ void fill_kernel(const int* __restrict__ src, const int* __restrict__ dst,
                            int* __restrict__ cursor, int* __restrict__ csr, int E) {
    int e = blockIdx.x * 256 + threadIdx.x;
    if (e < E) {
        int n = dst[e];
        int p = atomicAdd(&cursor[n], 1);
        csr[p] = src[e];
    }
}

// ---------------- fused aggregate + dual GEMM + bias ----------------
// out[n][o] = b[o] + sum_k feat[n][k]*Ws[o][k] + (1/max(deg,1)) sum_k summed[n][k]*Wn[o][k]

__global__ __launch_bounds__(256) void main_kernel(
        const float* __restrict__ feat,
        const int* __restrict__ csr, const int* __restrict__ rowptr,
        const int* __restrict__ count,
        const float* __restrict__ Wn, const float* __restrict__ Ws,
        const float* __restrict__ b_self,
        float* __restrict__ out) {
    __shared__ __align__(16) float shF[NB][F];   // feat rows
    __shared__ __align__(16) float shH[NB][F];   // mean-aggregated rows
    __shared__ __align__(16) float wts[32][F];   // W_self chunk, [k][o]
    __shared__ __align__(16) float wtn[32][F];   // W_neigh chunk, [k][o]

    const int tid = threadIdx.x;
    const int nb = blockIdx.x * NB;

    // ---- Phase A: aggregate (mean of neighbor feat rows) ----
    {
        const int g = tid >> 5;   // 8 groups of 32 lanes
        const int l = tid & 31;   // lane handles floats [4l, 4l+4)
        for (int i = g; i < NB; i += 8) {
            const int n = nb + i;
            const int rp = rowptr[n];
            const int cnt = count[n];
            float ax = 0.f, ay = 0.f, az = 0.f, aw = 0.f;
            for (int j = 0; j < cnt; ++j) {
                const int s = csr[rp + j];
                const float4 v = *reinterpret_cast<const float4*>(feat + (size_t)s * F + l * 4);
                ax += v.x; ay += v.y; az += v.z; aw += v.w;
            }
            const float dv = fmaxf((float)cnt, 1.0f);
            float4 h;
            h.x = ax / dv; h.y = ay / dv; h.z = az / dv; h.w = aw / dv;
            const float4 fv = *reinterpret_cast<const float4*>(feat + (size_t)n * F + l * 4);
            reinterpret_cast<float4*>(&shF[i][0])[l] = fv;
            reinterpret_cast<float4*>(&shH[i][0])[l] = h;
        }
    }
    __syncthreads();

    // ---- Phase B: dual GEMM ----
    const int oc = tid & 63;   // output pair index: outputs 2*oc, 2*oc+1
    const int ng = tid >> 6;   // node group: nodes ng*4 .. ng*4+3
    float acc[4][2];
#pragma unroll
    for (int i = 0; i < 4; ++i) { acc[i][0] = 0.f; acc[i][1] = 0.f; }

    for (int kc = 0; kc < 4; ++kc) {
        // stage transposed W chunk: wts[kk][o] = Ws[o][kc*32+kk]
        {
            const int o_l = tid >> 1;
            const int k0 = (tid & 1) * 16;
            const float* gs = Ws + o_l * F + kc * 32 + k0;
            const float* gn = Wn + o_l * F + kc * 32 + k0;
#pragma unroll
            for (int j = 0; j < 16; ++j) {
                wts[k0 + j][o_l] = gs[j];
                wtn[k0 + j][o_l] = gn[j];
            }
        }
        __syncthreads();

#pragma unroll
        for (int kk4 = 0; kk4 < 32; kk4 += 4) {
            float4 fA[4], hA[4];
#pragma unroll
            for (int i = 0; i < 4; ++i) {
                const int node = ng * 4 + i;
                fA[i] = reinterpret_cast<const float4*>(&shF[node][0])[(kc * 32 + kk4) >> 2];
                hA[i] = reinterpret_cast<const float4*>(&shH[node][0])[(kc * 32 + kk4) >> 2];
            }
#pragma unroll
            for (int j = 0; j < 4; ++j) {
                const float2 wsv = *reinterpret_cast<const float2*>(&wts[kk4 + j][oc * 2]);
                const float2 wnv = *reinterpret_cast<const float2*>(&wtn[kk4 + j][oc * 2]);
#pragma unroll
                for (int i = 0; i < 4; ++i) {
                    const float fa = (&fA[i].x)[j];
                    const float ha = (&hA[i].x)[j];
                    acc[i][0] += fa * wsv.x + ha * wnv.x;
                    acc[i][1] += fa * wsv.y + ha * wnv.y;
                }
            }
        }
        __syncthreads();
    }

    // ---- epilogue: bias + store ----
    const float b0 = b_self[oc * 2];
    const float b1 = b_self[oc * 2 + 1];
#pragma unroll
    for (int i = 0; i < 4; ++i) {
        const int n = nb + ng * 4 + i;
        float2 o2;
        o2.x = acc[i][0] + b0;
        o2.y = acc[i][1] + b1;
        *reinterpret_cast<float2*>(out + (size_t)n * F + oc * 2) = o2;
    }
}

// ---------------- launch ----------------

extern "C" void kernel_launch(void* const* d_in, const int* in_sizes, int n_in,
                              void* d_out, int out_size, void* d_ws, size_t ws_size,
                              hipStream_t stream) {
    const float* feat = (const float*)d_in[0];
    const int* src    = (const int*)d_in[1];
    const int* dst    = (const int*)d_in[2];
    const float* Wn   = (const float*)d_in[3];
    const float* Ws   = (const float*)d_in[4];
    const float* bs   = (const float*)d_in[5];
    float* out        = (float*)d_out;

    int* count  = (int*)d_ws;
    int* rowptr = count + N_NODES;
    int* cursor = rowptr + N_NODES;
    int* csr    = cursor + N_NODES;
    int* bsums  = csr + N_EDGES;

    const int nb1 = (N_NODES + 1023) / 1024;  // 98

    hipMemsetAsync(count, 0, N_NODES * sizeof(int), stream);
    hist_kernel<<<(N_EDGES + 255) / 256, 256, 0, stream>>>(dst, count, N_EDGES);
    scan1_kernel<<<nb1, 256, 0, stream>>>(count, rowptr, bsums, N_NODES);
    scan2_kernel<<<1, 256, 0, stream>>>(bsums, nb1);
    scan3_kernel<<<(N_NODES + 255) / 256, 256, 0, stream>>>(rowptr, bsums, cursor, N_NODES);
    fill_kernel<<<(N_EDGES + 255) / 256, 256, 0, stream>>>(src, dst, cursor, csr, N_EDGES);
    main_kernel<<<N_NODES / NB, 256, 0, stream>>>(feat, csr, rowptr, count, Wn, Ws, bs, out);
}

// Round 2
// 397.256 us; speedup vs baseline: 1.2721x; 1.2721x over previous
//
#include <hip/hip_runtime.h>

#define N_NODES 100000
#define N_EDGES 800000
#define F 128
#define NB 16   // nodes per block in fallback fused kernel
#define BM 64   // nodes per block in split gemm kernel

// ---------------- CSR build ----------------

__global__ void hist_kernel(const int* __restrict__ dst, int* __restrict__ count, int E) {
    int e = blockIdx.x * 256 + threadIdx.x;
    if (e < E) atomicAdd(&count[dst[e]], 1);
}

// Per-block exclusive scan of 1024 elements (256 thr x 4), block totals to bsums.
__global__ void scan1_kernel(const int* __restrict__ count, int* __restrict__ rowptr,
                             int* __restrict__ bsums, int N) {
    __shared__ int s[256];
    int tid = threadIdx.x;
    int base = blockIdx.x * 1024 + tid * 4;
    int c[4];
    int tsum = 0;
#pragma unroll
    for (int j = 0; j < 4; ++j) {
        int idx = base + j;
        c[j] = (idx < N) ? count[idx] : 0;
        tsum += c[j];
    }
    s[tid] = tsum;
    __syncthreads();
    for (int off = 1; off < 256; off <<= 1) {
        int u = (tid >= off) ? s[tid - off] : 0;
        __syncthreads();
        s[tid] += u;
        __syncthreads();
    }
    int incl = s[tid];
    int run = incl - tsum;
#pragma unroll
    for (int j = 0; j < 4; ++j) {
        int idx = base + j;
        if (idx < N) rowptr[idx] = run;
        run += c[j];
    }
    if (tid == 255) bsums[blockIdx.x] = incl;
}

__global__ void scan2_kernel(int* __restrict__ bsums, int nb) {
    __shared__ int s[256];
    int tid = threadIdx.x;
    int v = (tid < nb) ? bsums[tid] : 0;
    s[tid] = v;
    __syncthreads();
    for (int off = 1; off < 256; off <<= 1) {
        int u = (tid >= off) ? s[tid - off] : 0;
        __syncthreads();
        s[tid] += u;
        __syncthreads();
    }
    int excl = s[tid] - v;
    if (tid < nb) bsums[tid] = excl;
}

__global__ void scan3_kernel(int* __restrict__ rowptr, const int* __restrict__ bsums,
                             int* __restrict__ cursor, int N) {
    int i = blockIdx.x * 256 + threadIdx.x;
    if (i < N) {
        int r = rowptr[i] + bsums[i >> 10];
        rowptr[i] = r;
        cursor[i] = r;
    }
}

__global__ void fill_kernel(const int* __restrict__ src, const int* __restrict__ dst,
                            int* __restrict__ cursor, int* __restrict__ csr, int E) {
    int e = blockIdx.x * 256 + threadIdx.x;
    if (e < E) {
        int n = dst[e];
        int p = atomicAdd(&cursor[n], 1);
        csr[p] = src[e];
    }
}

// ---------------- split path: dense dual GEMM ----------------
// out[n][o] = b[o] + sum_k feat[n][k]*Ws[o][k]    (self part)
// Y[n][o]   =        sum_k feat[n][k]*Wn[o][k]    (to be mean-aggregated later)

__global__ __launch_bounds__(256) void gemm_kernel(
        const float* __restrict__ feat,
        const float* __restrict__ Wn, const float* __restrict__ Ws,
        const float* __restrict__ b_self,
        float* __restrict__ out, float* __restrict__ Y) {
    __shared__ __align__(16) float shF[BM][F];   // 32 KB feat tile
    __shared__ __align__(16) float wls[32][F];   // W_self chunk transposed [k][o], 16 KB
    __shared__ __align__(16) float wln[32][F];   // W_neigh chunk transposed, 16 KB

    const int tid = threadIdx.x;
    const int nb = blockIdx.x * BM;

    // stage feat tile: thread -> row tid/4, col chunk (tid%4)*32
    {
        const int row = tid >> 2;
        const int c0 = (tid & 3) * 32;
        int n = nb + row;
        if (n >= N_NODES) n = N_NODES - 1;  // clamp (value unused on store side)
        const float4* gsrc = reinterpret_cast<const float4*>(feat + (size_t)n * F + c0);
        float4* ldst = reinterpret_cast<float4*>(&shF[row][c0]);
#pragma unroll
        for (int j = 0; j < 8; ++j) ldst[j] = gsrc[j];
    }

    const int oc = tid & 63;   // outputs 2*oc, 2*oc+1
    const int grp = tid >> 6;  // nodes grp*16 .. grp*16+15

    float acc_s[16][2], acc_n[16][2];
#pragma unroll
    for (int i = 0; i < 16; ++i) {
        acc_s[i][0] = 0.f; acc_s[i][1] = 0.f;
        acc_n[i][0] = 0.f; acc_n[i][1] = 0.f;
    }

    for (int kc = 0; kc < 4; ++kc) {
        __syncthreads();
        // stage W chunk transposed: 128 threads per matrix, one output row each
        {
            const int mat = tid >> 7;
            const int o = tid & 127;
            const float* g = (mat ? Wn : Ws) + (size_t)o * F + kc * 32;
            float* l = mat ? &wln[0][0] : &wls[0][0];
#pragma unroll
            for (int j = 0; j < 8; ++j) {
                const float4 v = reinterpret_cast<const float4*>(g)[j];
                l[(j * 4 + 0) * F + o] = v.x;
                l[(j * 4 + 1) * F + o] = v.y;
                l[(j * 4 + 2) * F + o] = v.z;
                l[(j * 4 + 3) * F + o] = v.w;
            }
        }
        __syncthreads();

#pragma unroll
        for (int k4 = 0; k4 < 8; ++k4) {
            float2 ws[4], wn[4];
#pragma unroll
            for (int j = 0; j < 4; ++j) {
                ws[j] = *reinterpret_cast<const float2*>(&wls[k4 * 4 + j][oc * 2]);
                wn[j] = *reinterpret_cast<const float2*>(&wln[k4 * 4 + j][oc * 2]);
            }
#pragma unroll
            for (int i = 0; i < 16; ++i) {
                const float4 fA = reinterpret_cast<const float4*>(&shF[grp * 16 + i][0])[kc * 8 + k4];
#pragma unroll
                for (int j = 0; j < 4; ++j) {
                    const float fa = (&fA.x)[j];
                    acc_s[i][0] = fmaf(fa, ws[j].x, acc_s[i][0]);
                    acc_s[i][1] = fmaf(fa, ws[j].y, acc_s[i][1]);
                    acc_n[i][0] = fmaf(fa, wn[j].x, acc_n[i][0]);
                    acc_n[i][1] = fmaf(fa, wn[j].y, acc_n[i][1]);
                }
            }
        }
    }

    const float b0 = b_self[oc * 2];
    const float b1 = b_self[oc * 2 + 1];
#pragma unroll
    for (int i = 0; i < 16; ++i) {
        const int n = nb + grp * 16 + i;
        if (n < N_NODES) {
            float2 o2, y2;
            o2.x = acc_s[i][0] + b0; o2.y = acc_s[i][1] + b1;
            y2.x = acc_n[i][0];      y2.y = acc_n[i][1];
            *reinterpret_cast<float2*>(out + (size_t)n * F + oc * 2) = o2;
            *reinterpret_cast<float2*>(Y + (size_t)n * F + oc * 2) = y2;
        }
    }
}

// ---------------- split path: gather-mean of Y, add into out ----------------

__global__ __launch_bounds__(256) void agg_kernel(
        const float* __restrict__ Y,
        const int* __restrict__ csr, const int* __restrict__ rowptr,
        const int* __restrict__ count,
        float* __restrict__ out) {
    const int node = blockIdx.x * 4 + (threadIdx.x >> 6);
    const int lane = threadIdx.x & 63;
    if (node >= N_NODES) return;

    const int rp = __builtin_amdgcn_readfirstlane(rowptr[node]);
    const int cnt = __builtin_amdgcn_readfirstlane(count[node]);

    float a0x = 0.f, a0y = 0.f, a1x = 0.f, a1y = 0.f;
    float a2x = 0.f, a2y = 0.f, a3x = 0.f, a3y = 0.f;

    int j = 0;
    for (; j + 4 <= cnt; j += 4) {
        const int i0 = csr[rp + j];
        const int i1 = csr[rp + j + 1];
        const int i2 = csr[rp + j + 2];
        const int i3 = csr[rp + j + 3];
        const float2 v0 = *reinterpret_cast<const float2*>(Y + (size_t)i0 * F + lane * 2);
        const float2 v1 = *reinterpret_cast<const float2*>(Y + (size_t)i1 * F + lane * 2);
        const float2 v2 = *reinterpret_cast<const float2*>(Y + (size_t)i2 * F + lane * 2);
        const float2 v3 = *reinterpret_cast<const float2*>(Y + (size_t)i3 * F + lane * 2);
        a0x += v0.x; a0y += v0.y;
        a1x += v1.x; a1y += v1.y;
        a2x += v2.x; a2y += v2.y;
        a3x += v3.x; a3y += v3.y;
    }
    for (; j < cnt; ++j) {
        const int i0 = csr[rp + j];
        const float2 v0 = *reinterpret_cast<const float2*>(Y + (size_t)i0 * F + lane * 2);
        a0x += v0.x; a0y += v0.y;
    }

    const float inv = 1.0f / fmaxf((float)cnt, 1.0f);
    const float sx = (a0x + a1x) + (a2x + a3x);
    const float sy = (a0y + a1y) + (a2y + a3y);

    float2* op = reinterpret_cast<float2*>(out + (size_t)node * F) + lane;
    float2 cur = *op;
    cur.x += sx * inv;
    cur.y += sy * inv;
    *op = cur;
}

// ---------------- fallback fused kernel (round-1, known-good) ----------------

__global__ __launch_bounds__(256) void main_kernel(
        const float* __restrict__ feat,
        const int* __restrict__ csr, const int* __restrict__ rowptr,
        const int* __restrict__ count,
        const float* __restrict__ Wn, const float* __restrict__ Ws,
        const float* __restrict__ b_self,
        float* __restrict__ out) {
    __shared__ __align__(16) float shF[NB][F];
    __shared__ __align__(16) float shH[NB][F];
    __shared__ __align__(16) float wts[32][F];
    __shared__ __align__(16) float wtn[32][F];

    const int tid = threadIdx.x;
    const int nb = blockIdx.x * NB;

    {
        const int g = tid >> 5;
        const int l = tid & 31;
        for (int i = g; i < NB; i += 8) {
            const int n = nb + i;
            const int rp = rowptr[n];
            const int cnt = count[n];
            float ax = 0.f, ay = 0.f, az = 0.f, aw = 0.f;
            for (int j = 0; j < cnt; ++j) {
                const int s = csr[rp + j];
                const float4 v = *reinterpret_cast<const float4*>(feat + (size_t)s * F + l * 4);
                ax += v.x; ay += v.y; az += v.z; aw += v.w;
            }
            const float dv = fmaxf((float)cnt, 1.0f);
            float4 h;
            h.x = ax / dv; h.y = ay / dv; h.z = az / dv; h.w = aw / dv;
            const float4 fv = *reinterpret_cast<const float4*>(feat + (size_t)n * F + l * 4);
            reinterpret_cast<float4*>(&shF[i][0])[l] = fv;
            reinterpret_cast<float4*>(&shH[i][0])[l] = h;
        }
    }
    __syncthreads();

    const int oc = tid & 63;
    const int ng = tid >> 6;
    float acc[4][2];
#pragma unroll
    for (int i = 0; i < 4; ++i) { acc[i][0] = 0.f; acc[i][1] = 0.f; }

    for (int kc = 0; kc < 4; ++kc) {
        {
            const int o_l = tid >> 1;
            const int k0 = (tid & 1) * 16;
            const float* gs = Ws + o_l * F + kc * 32 + k0;
            const float* gn = Wn + o_l * F + kc * 32 + k0;
#pragma unroll
            for (int j = 0; j < 16; ++j) {
                wts[k0 + j][o_l] = gs[j];
                wtn[k0 + j][o_l] = gn[j];
            }
        }
        __syncthreads();

#pragma unroll
        for (int kk4 = 0; kk4 < 32; kk4 += 4) {
            float4 fA[4], hA[4];
#pragma unroll
            for (int i = 0; i < 4; ++i) {
                const int node = ng * 4 + i;
                fA[i] = reinterpret_cast<const float4*>(&shF[node][0])[(kc * 32 + kk4) >> 2];
                hA[i] = reinterpret_cast<const float4*>(&shH[node][0])[(kc * 32 + kk4) >> 2];
            }
#pragma unroll
            for (int j = 0; j < 4; ++j) {
                const float2 wsv = *reinterpret_cast<const float2*>(&wts[kk4 + j][oc * 2]);
                const float2 wnv = *reinterpret_cast<const float2*>(&wtn[kk4 + j][oc * 2]);
#pragma unroll
                for (int i = 0; i < 4; ++i) {
                    const float fa = (&fA[i].x)[j];
                    const float ha = (&hA[i].x)[j];
                    acc[i][0] += fa * wsv.x + ha * wnv.x;
                    acc[i][1] += fa * wsv.y + ha * wnv.y;
                }
            }
        }
        __syncthreads();
    }

    const float b0 = b_self[oc * 2];
    const float b1 = b_self[oc * 2 + 1];
#pragma unroll
    for (int i = 0; i < 4; ++i) {
        const int n = nb + ng * 4 + i;
        float2 o2;
        o2.x = acc[i][0] + b0;
        o2.y = acc[i][1] + b1;
        *reinterpret_cast<float2*>(out + (size_t)n * F + oc * 2) = o2;
    }
}

// ---------------- launch ----------------

extern "C" void kernel_launch(void* const* d_in, const int* in_sizes, int n_in,
                              void* d_out, int out_size, void* d_ws, size_t ws_size,
                              hipStream_t stream) {
    const float* feat = (const float*)d_in[0];
    const int* src    = (const int*)d_in[1];
    const int* dst    = (const int*)d_in[2];
    const float* Wn   = (const float*)d_in[3];
    const float* Ws   = (const float*)d_in[4];
    const float* bs   = (const float*)d_in[5];
    float* out        = (float*)d_out;

    const size_t y_floats = (size_t)N_NODES * F;
    const size_t int_words = (size_t)3 * N_NODES + N_EDGES + 256;
    const size_t need = (y_floats + int_words) * sizeof(float);
    const int nb1 = (N_NODES + 1023) / 1024;  // 98

    if (ws_size >= need) {
        // ---- split path ----
        float* Y    = (float*)d_ws;
        int* count  = (int*)(Y + y_floats);
        int* rowptr = count + N_NODES;
        int* cursor = rowptr + N_NODES;
        int* csr    = cursor + N_NODES;
        int* bsums  = csr + N_EDGES;

        hipMemsetAsync(count, 0, N_NODES * sizeof(int), stream);
        hist_kernel<<<(N_EDGES + 255) / 256, 256, 0, stream>>>(dst, count, N_EDGES);
        scan1_kernel<<<nb1, 256, 0, stream>>>(count, rowptr, bsums, N_NODES);
        scan2_kernel<<<1, 256, 0, stream>>>(bsums, nb1);
        scan3_kernel<<<(N_NODES + 255) / 256, 256, 0, stream>>>(rowptr, bsums, cursor, N_NODES);
        fill_kernel<<<(N_EDGES + 255) / 256, 256, 0, stream>>>(src, dst, cursor, csr, N_EDGES);
        gemm_kernel<<<(N_NODES + BM - 1) / BM, 256, 0, stream>>>(feat, Wn, Ws, bs, out, Y);
        agg_kernel<<<(N_NODES + 3) / 4, 256, 0, stream>>>(Y, csr, rowptr, count, out);
    } else {
        // ---- fallback fused path ----
        int* count  = (int*)d_ws;
        int* rowptr = count + N_NODES;
        int* cursor = rowptr + N_NODES;
        int* csr    = cursor + N_NODES;
        int* bsums  = csr + N_EDGES;

        hipMemsetAsync(count, 0, N_NODES * sizeof(int), stream);
        hist_kernel<<<(N_EDGES + 255) / 256, 256, 0, stream>>>(dst, count, N_EDGES);
        scan1_kernel<<<nb1, 256, 0, stream>>>(count, rowptr, bsums, N_NODES);
        scan2_kernel<<<1, 256, 0, stream>>>(bsums, nb1);
        scan3_kernel<<<(N_NODES + 255) / 256, 256, 0, stream>>>(rowptr, bsums, cursor, N_NODES);
        fill_kernel<<<(N_EDGES + 255) / 256, 256, 0, stream>>>(src, dst, cursor, csr, N_EDGES);
        main_kernel<<<N_NODES / NB, 256, 0, stream>>>(feat, csr, rowptr, count, Wn, Ws, bs, out);
    }
}

// Round 3
// 288.682 us; speedup vs baseline: 1.7505x; 1.3761x over previous
//
#include <hip/hip_runtime.h>

#define N_NODES 100000
#define N_EDGES 800000
#define F 128
#define NB 16   // nodes per block in fallback fused kernel
#define BM 64   // nodes per block in mfma gemm kernel

typedef __attribute__((ext_vector_type(8))) short bf16x8;
typedef __attribute__((ext_vector_type(4))) float f32x4;

// ---------------- CSR build ----------------

__global__ void hist_kernel(const int* __restrict__ dst, int* __restrict__ count, int E) {
    int e = blockIdx.x * 256 + threadIdx.x;
    if (e < E) atomicAdd(&count[dst[e]], 1);
}

__global__ void scan1_kernel(const int* __restrict__ count, int* __restrict__ rowptr,
                             int* __restrict__ bsums, int N) {
    __shared__ int s[256];
    int tid = threadIdx.x;
    int base = blockIdx.x * 1024 + tid * 4;
    int c[4];
    int tsum = 0;
#pragma unroll
    for (int j = 0; j < 4; ++j) {
        int idx = base + j;
        c[j] = (idx < N) ? count[idx] : 0;
        tsum += c[j];
    }
    s[tid] = tsum;
    __syncthreads();
    for (int off = 1; off < 256; off <<= 1) {
        int u = (tid >= off) ? s[tid - off] : 0;
        __syncthreads();
        s[tid] += u;
        __syncthreads();
    }
    int incl = s[tid];
    int run = incl - tsum;
#pragma unroll
    for (int j = 0; j < 4; ++j) {
        int idx = base + j;
        if (idx < N) rowptr[idx] = run;
        run += c[j];
    }
    if (tid == 255) bsums[blockIdx.x] = incl;
}

__global__ void scan2_kernel(int* __restrict__ bsums, int nb) {
    __shared__ int s[256];
    int tid = threadIdx.x;
    int v = (tid < nb) ? bsums[tid] : 0;
    s[tid] = v;
    __syncthreads();
    for (int off = 1; off < 256; off <<= 1) {
        int u = (tid >= off) ? s[tid - off] : 0;
        __syncthreads();
        s[tid] += u;
        __syncthreads();
    }
    int excl = s[tid] - v;
    if (tid < nb) bsums[tid] = excl;
}

__global__ void scan3_kernel(int* __restrict__ rowptr, const int* __restrict__ bsums,
                             int* __restrict__ cursor, int N) {
    int i = blockIdx.x * 256 + threadIdx.x;
    if (i < N) {
        int r = rowptr[i] + bsums[i >> 10];
        rowptr[i] = r;
        cursor[i] = r;
    }
}

__global__ void fill_kernel(const int* __restrict__ src, const int* __restrict__ dst,
                            int* __restrict__ cursor, int* __restrict__ csr, int E) {
    int e = blockIdx.x * 256 + threadIdx.x;
    if (e < E) {
        int n = dst[e];
        int p = atomicAdd(&cursor[n], 1);
        csr[p] = src[e];
    }
}

// ---------------- W fragment prep (split-bf16, fragment-linear) ----------------
// Global col n in [0,256): n<128 -> W_self row n (feeds out), n>=128 -> W_neigh row n-128 (feeds Y).
// Fragment f = (ntile*4 + ks)*64 + lane holds B[k = ks*32 + (lane>>4)*8 + e][n0 + (lane&15)]
// i.e. 8 contiguous k of W row n. hi region = first 4096 frags, lo region next 4096.

__global__ void wprep_kernel(const float* __restrict__ Ws, const float* __restrict__ Wn,
                             short* __restrict__ wf) {
    int t = blockIdx.x * 256 + threadIdx.x;  // 0..1023
    if (t >= 1024) return;
    int n = t >> 2;
    int ks = t & 3;
    const float* row = (n < 128) ? (Ws + (size_t)n * F) : (Wn + (size_t)(n - 128) * F);
    int ntile = n >> 4;
#pragma unroll
    for (int g = 0; g < 4; ++g) {
        int lane = (n & 15) + 16 * g;
        size_t base = ((size_t)(ntile * 4 + ks) * 64 + lane) * 8;
#pragma unroll
        for (int e = 0; e < 8; ++e) {
            float x = row[ks * 32 + g * 8 + e];
            unsigned xb = __float_as_uint(x);
            unsigned hb = xb & 0xFFFF0000u;
            float lo = x - __uint_as_float(hb);
            wf[base + e] = (short)(hb >> 16);
            wf[32768 + base + e] = (short)(__float_as_uint(lo) >> 16);
        }
    }
}

// ---------------- MFMA dual GEMM: out = feat@Ws^T + b ; Y = feat@Wn^T ----------------
// Split-bf16: x = hi + lo (truncated bf16 halves); product uses HH + HL + LH terms.

__global__ __launch_bounds__(256, 3) void gemm_mfma_kernel(
        const float* __restrict__ feat,
        const short* __restrict__ wf,
        const float* __restrict__ b_self,
        float* __restrict__ out, float* __restrict__ Y) {
    // A fragments, fragment-linear: [hi/lo][(ks<<2)|mtile][lane] -> 8 bf16 (16 B). 32 KB.
    __shared__ bf16x8 aF[2][16][64];

    const int tid = threadIdx.x;
    const int nb = blockIdx.x * BM;

    // ---- stage A: read 64x128 feat tile coalesced, split to hi/lo bf16, frag-linear LDS ----
    {
        const int r = tid >> 2;     // row in tile 0..63
        const int ks = tid & 3;     // k-chunk of 32
        int n = nb + r;
        if (n >= N_NODES) n = N_NODES - 1;  // clamp; stores are guarded later
        float4 v[8];
        const float4* g = reinterpret_cast<const float4*>(feat + (size_t)n * F + ks * 32);
#pragma unroll
        for (int j = 0; j < 8; ++j) v[j] = g[j];
        const float* vv = &v[0].x;
        const int mt = r >> 4;
        const int l0 = r & 15;
#pragma unroll
        for (int g5 = 0; g5 < 4; ++g5) {
            bf16x8 hi8, lo8;
#pragma unroll
            for (int e = 0; e < 8; ++e) {
                float x = vv[g5 * 8 + e];
                unsigned xb = __float_as_uint(x);
                unsigned hb = xb & 0xFFFF0000u;
                float lo = x - __uint_as_float(hb);
                hi8[e] = (short)(hb >> 16);
                lo8[e] = (short)(__float_as_uint(lo) >> 16);
            }
            aF[0][(ks << 2) | mt][l0 + 16 * g5] = hi8;
            aF[1][(ks << 2) | mt][l0 + 16 * g5] = lo8;
        }
    }
    __syncthreads();

    const int wv = tid >> 6;     // wave 0..3 -> global cols [wv*64, wv*64+64)
    const int lane = tid & 63;

    f32x4 acc[4][4];             // [mtile][ntile-within-wave]
#pragma unroll
    for (int t = 0; t < 4; ++t)
#pragma unroll
        for (int j = 0; j < 4; ++j)
            acc[t][j] = (f32x4){0.f, 0.f, 0.f, 0.f};

    const bf16x8* wfh = reinterpret_cast<const bf16x8*>(wf);
    const bf16x8* wfl = wfh + 4096;

#pragma unroll
    for (int ks = 0; ks < 4; ++ks) {
        bf16x8 ah[4], al[4], bh[4], bl[4];
#pragma unroll
        for (int t = 0; t < 4; ++t) {
            ah[t] = aF[0][(ks << 2) | t][lane];
            al[t] = aF[1][(ks << 2) | t][lane];
        }
#pragma unroll
        for (int j = 0; j < 4; ++j) {
            const int ntile = wv * 4 + j;
            bh[j] = wfh[(ntile * 4 + ks) * 64 + lane];
            bl[j] = wfl[(ntile * 4 + ks) * 64 + lane];
        }
#pragma unroll
        for (int t = 0; t < 4; ++t)
#pragma unroll
            for (int j = 0; j < 4; ++j) {
                acc[t][j] = __builtin_amdgcn_mfma_f32_16x16x32_bf16(ah[t], bh[j], acc[t][j], 0, 0, 0);
                acc[t][j] = __builtin_amdgcn_mfma_f32_16x16x32_bf16(ah[t], bl[j], acc[t][j], 0, 0, 0);
                acc[t][j] = __builtin_amdgcn_mfma_f32_16x16x32_bf16(al[t], bh[j], acc[t][j], 0, 0, 0);
            }
    }

    // ---- epilogue: C/D layout col=lane&15, row=(lane>>4)*4+reg ----
    const bool isOut = (wv < 2);
#pragma unroll
    for (int t = 0; t < 4; ++t) {
        const int m0 = nb + t * 16 + ((lane >> 4) << 2);
#pragma unroll
        for (int j = 0; j < 4; ++j) {
            const int col = wv * 64 + j * 16 + (lane & 15);
            if (isOut) {
                const float b = b_self[col];
#pragma unroll
                for (int r = 0; r < 4; ++r) {
                    const int m = m0 + r;
                    if (m < N_NODES) out[(size_t)m * F + col] = acc[t][j][r] + b;
                }
            } else {
#pragma unroll
                for (int r = 0; r < 4; ++r) {
                    const int m = m0 + r;
                    if (m < N_NODES) Y[(size_t)m * F + (col - 128)] = acc[t][j][r];
                }
            }
        }
    }
}

// ---------------- gather-mean of Y, add into out ----------------

__global__ __launch_bounds__(256) void agg_kernel(
        const float* __restrict__ Y,
        const int* __restrict__ csr, const int* __restrict__ rowptr,
        const int* __restrict__ count,
        float* __restrict__ out) {
    const int node = blockIdx.x * 4 + (threadIdx.x >> 6);
    const int lane = threadIdx.x & 63;
    if (node >= N_NODES) return;

    const int rp = __builtin_amdgcn_readfirstlane(rowptr[node]);
    const int cnt = __builtin_amdgcn_readfirstlane(count[node]);

    float a0x = 0.f, a0y = 0.f, a1x = 0.f, a1y = 0.f;
    float a2x = 0.f, a2y = 0.f, a3x = 0.f, a3y = 0.f;

    int j = 0;
    for (; j + 4 <= cnt; j += 4) {
        const int i0 = csr[rp + j];
        const int i1 = csr[rp + j + 1];
        const int i2 = csr[rp + j + 2];
        const int i3 = csr[rp + j + 3];
        const float2 v0 = *reinterpret_cast<const float2*>(Y + (size_t)i0 * F + lane * 2);
        const float2 v1 = *reinterpret_cast<const float2*>(Y + (size_t)i1 * F + lane * 2);
        const float2 v2 = *reinterpret_cast<const float2*>(Y + (size_t)i2 * F + lane * 2);
        const float2 v3 = *reinterpret_cast<const float2*>(Y + (size_t)i3 * F + lane * 2);
        a0x += v0.x; a0y += v0.y;
        a1x += v1.x; a1y += v1.y;
        a2x += v2.x; a2y += v2.y;
        a3x += v3.x; a3y += v3.y;
    }
    for (; j < cnt; ++j) {
        const int i0 = csr[rp + j];
        const float2 v0 = *reinterpret_cast<const float2*>(Y + (size_t)i0 * F + lane * 2);
        a0x += v0.x; a0y += v0.y;
    }

    const float inv = 1.0f / fmaxf((float)cnt, 1.0f);
    const float sx = (a0x + a1x) + (a2x + a3x);
    const float sy = (a0y + a1y) + (a2y + a3y);

    float2* op = reinterpret_cast<float2*>(out + (size_t)node * F) + lane;
    float2 cur = *op;
    cur.x += sx * inv;
    cur.y += sy * inv;
    *op = cur;
}

// ---------------- fallback fused kernel (round-1, known-good) ----------------

__global__ __launch_bounds__(256) void main_kernel(
        const float* __restrict__ feat,
        const int* __restrict__ csr, const int* __restrict__ rowptr,
        const int* __restrict__ count,
        const float* __restrict__ Wn, const float* __restrict__ Ws,
        const float* __restrict__ b_self,
        float* __restrict__ out) {
    __shared__ __align__(16) float shF[NB][F];
    __shared__ __align__(16) float shH[NB][F];
    __shared__ __align__(16) float wts[32][F];
    __shared__ __align__(16) float wtn[32][F];

    const int tid = threadIdx.x;
    const int nb = blockIdx.x * NB;

    {
        const int g = tid >> 5;
        const int l = tid & 31;
        for (int i = g; i < NB; i += 8) {
            const int n = nb + i;
            const int rp = rowptr[n];
            const int cnt = count[n];
            float ax = 0.f, ay = 0.f, az = 0.f, aw = 0.f;
            for (int j = 0; j < cnt; ++j) {
                const int s = csr[rp + j];
                const float4 v = *reinterpret_cast<const float4*>(feat + (size_t)s * F + l * 4);
                ax += v.x; ay += v.y; az += v.z; aw += v.w;
            }
            const float dv = fmaxf((float)cnt, 1.0f);
            float4 h;
            h.x = ax / dv; h.y = ay / dv; h.z = az / dv; h.w = aw / dv;
            const float4 fv = *reinterpret_cast<const float4*>(feat + (size_t)n * F + l * 4);
            reinterpret_cast<float4*>(&shF[i][0])[l] = fv;
            reinterpret_cast<float4*>(&shH[i][0])[l] = h;
        }
    }
    __syncthreads();

    const int oc = tid & 63;
    const int ng = tid >> 6;
    float acc[4][2];
#pragma unroll
    for (int i = 0; i < 4; ++i) { acc[i][0] = 0.f; acc[i][1] = 0.f; }

    for (int kc = 0; kc < 4; ++kc) {
        {
            const int o_l = tid >> 1;
            const int k0 = (tid & 1) * 16;
            const float* gs = Ws + o_l * F + kc * 32 + k0;
            const float* gn = Wn + o_l * F + kc * 32 + k0;
#pragma unroll
            for (int j = 0; j < 16; ++j) {
                wts[k0 + j][o_l] = gs[j];
                wtn[k0 + j][o_l] = gn[j];
            }
        }
        __syncthreads();

#pragma unroll
        for (int kk4 = 0; kk4 < 32; kk4 += 4) {
            float4 fA[4], hA[4];
#pragma unroll
            for (int i = 0; i < 4; ++i) {
                const int node = ng * 4 + i;
                fA[i] = reinterpret_cast<const float4*>(&shF[node][0])[(kc * 32 + kk4) >> 2];
                hA[i] = reinterpret_cast<const float4*>(&shH[node][0])[(kc * 32 + kk4) >> 2];
            }
#pragma unroll
            for (int j = 0; j < 4; ++j) {
                const float2 wsv = *reinterpret_cast<const float2*>(&wts[kk4 + j][oc * 2]);
                const float2 wnv = *reinterpret_cast<const float2*>(&wtn[kk4 + j][oc * 2]);
#pragma unroll
                for (int i = 0; i < 4; ++i) {
                    const float fa = (&fA[i].x)[j];
                    const float ha = (&hA[i].x)[j];
                    acc[i][0] += fa * wsv.x + ha * wnv.x;
                    acc[i][1] += fa * wsv.y + ha * wnv.y;
                }
            }
        }
        __syncthreads();
    }

    const float b0 = b_self[oc * 2];
    const float b1 = b_self[oc * 2 + 1];
#pragma unroll
    for (int i = 0; i < 4; ++i) {
        const int n = nb + ng * 4 + i;
        float2 o2;
        o2.x = acc[i][0] + b0;
        o2.y = acc[i][1] + b1;
        *reinterpret_cast<float2*>(out + (size_t)n * F + oc * 2) = o2;
    }
}

// ---------------- launch ----------------

extern "C" void kernel_launch(void* const* d_in, const int* in_sizes, int n_in,
                              void* d_out, int out_size, void* d_ws, size_t ws_size,
                              hipStream_t stream) {
    const float* feat = (const float*)d_in[0];
    const int* src    = (const int*)d_in[1];
    const int* dst    = (const int*)d_in[2];
    const float* Wn   = (const float*)d_in[3];
    const float* Ws   = (const float*)d_in[4];
    const float* bs   = (const float*)d_in[5];
    float* out        = (float*)d_out;

    const size_t y_floats = (size_t)N_NODES * F;
    const size_t wf_shorts = 65536;  // 2 x 4096 frags x 8 bf16 = 128 KB
    const size_t int_words = (size_t)3 * N_NODES + N_EDGES + 256;
    const size_t need = y_floats * 4 + wf_shorts * 2 + int_words * 4;
    const int nb1 = (N_NODES + 1023) / 1024;  // 98

    if (ws_size >= need) {
        // ---- MFMA split path ----
        float* Y    = (float*)d_ws;
        short* wf   = (short*)(Y + y_floats);
        int* count  = (int*)(wf + wf_shorts);
        int* rowptr = count + N_NODES;
        int* cursor = rowptr + N_NODES;
        int* csr    = cursor + N_NODES;
        int* bsums  = csr + N_EDGES;

        wprep_kernel<<<4, 256, 0, stream>>>(Ws, Wn, wf);
        hipMemsetAsync(count, 0, N_NODES * sizeof(int), stream);
        hist_kernel<<<(N_EDGES + 255) / 256, 256, 0, stream>>>(dst, count, N_EDGES);
        scan1_kernel<<<nb1, 256, 0, stream>>>(count, rowptr, bsums, N_NODES);
        scan2_kernel<<<1, 256, 0, stream>>>(bsums, nb1);
        scan3_kernel<<<(N_NODES + 255) / 256, 256, 0, stream>>>(rowptr, bsums, cursor, N_NODES);
        fill_kernel<<<(N_EDGES + 255) / 256, 256, 0, stream>>>(src, dst, cursor, csr, N_EDGES);
        gemm_mfma_kernel<<<(N_NODES + BM - 1) / BM, 256, 0, stream>>>(feat, wf, bs, out, Y);
        agg_kernel<<<(N_NODES + 3) / 4, 256, 0, stream>>>(Y, csr, rowptr, count, out);
    } else {
        // ---- fallback fused path ----
        int* count  = (int*)d_ws;
        int* rowptr = count + N_NODES;
        int* cursor = rowptr + N_NODES;
        int* csr    = cursor + N_NODES;
        int* bsums  = csr + N_EDGES;

        hipMemsetAsync(count, 0, N_NODES * sizeof(int), stream);
        hist_kernel<<<(N_EDGES + 255) / 256, 256, 0, stream>>>(dst, count, N_EDGES);
        scan1_kernel<<<nb1, 256, 0, stream>>>(count, rowptr, bsums, N_NODES);
        scan2_kernel<<<1, 256, 0, stream>>>(bsums, nb1);
        scan3_kernel<<<(N_NODES + 255) / 256, 256, 0, stream>>>(rowptr, bsums, cursor, N_NODES);
        fill_kernel<<<(N_EDGES + 255) / 256, 256, 0, stream>>>(src, dst, cursor, csr, N_EDGES);
        main_kernel<<<N_NODES / NB, 256, 0, stream>>>(feat, csr, rowptr, count, Wn, Ws, bs, out);
    }
}